// Round 7
// baseline (334.209 us; speedup 1.0000x reference)
//
#include <hip/hip_runtime.h>
#include <cstdint>

// Problem constants
#define B_    8
#define N_    1024
#define DIM_  768
#define H_    12
#define D_    64
#define SCALE_ 0.125f
#define GQ_   32   // partial-gram blocks per head for Q (8192 rows / 256)
#define GK_   4    // partial-gram blocks per head for K (1024 rows / 256)

typedef unsigned short u16;
typedef short bf16x8 __attribute__((ext_vector_type(8)));
typedef float f32x4  __attribute__((ext_vector_type(4)));

__device__ __forceinline__ u16 f2b(float f) {
  union { float f; unsigned u; } v; v.f = f;
  unsigned r = v.u + 0x7FFFu + ((v.u >> 16) & 1u);
  return (u16)(r >> 16);
}
// half-up round to bf16 (2 VALU ops; for positive non-NaN values)
__device__ __forceinline__ u16 phu(float f) {
  union { float f; unsigned u; } v; v.f = f;
  return (u16)((v.u + 0x8000u) >> 16);
}
__device__ __forceinline__ float b2f(u16 h) {
  union { unsigned u; float f; } v; v.u = ((unsigned)h) << 16; return v.f;
}
#if __has_builtin(__builtin_amdgcn_exp2f)
__device__ __forceinline__ float exp2fast(float x) { return __builtin_amdgcn_exp2f(x); }
#else
__device__ __forceinline__ float exp2fast(float x) { return __expf(x * 0.69314718f); }
#endif
// async global->LDS, 16B per lane; LDS base must be wave-uniform (HW adds lane*16)
__device__ __forceinline__ void gl2lds16(const void* g, void* l) {
  __builtin_amdgcn_global_load_lds(
      (const __attribute__((address_space(1))) void*)g,
      (__attribute__((address_space(3))) void*)l, 16, 0, 0);
}

// ---------------------------------------------------------------- K0: fp32 -> bf16 casts
// + branch-3 (ext_k) also writes k^T [H][64][1024]
// + block 0 zeroes the atomic-accumulator region (replaces hipMemsetAsync)
__global__ __launch_bounds__(256) void cast_all(
    const float4* __restrict__ s0, u16* __restrict__ d0, int n0,
    const float4* __restrict__ s1, u16* __restrict__ d1, int n1,
    const float4* __restrict__ s2, u16* __restrict__ d2, int n2,
    const float4* __restrict__ s3, u16* __restrict__ d3, int n3,
    u16* __restrict__ ktT, float* __restrict__ zptr, int zfloats)
{
  const int tid = threadIdx.x;
  if (blockIdx.x == 0)
    for (int j = tid; j < zfloats; j += 256) zptr[j] = 0.f;
  int i = blockIdx.x * 256 + tid;
  const float4* s; u16* d; int off; int br;
  if (i < n0)               { s = s0; d = d0; off = i; br = 0; }
  else if (i < n0+n1)       { s = s1; d = d1; off = i - n0; br = 1; }
  else if (i < n0+n1+n2)    { s = s2; d = d2; off = i - n0 - n1; br = 2; }
  else if (i < n0+n1+n2+n3) { s = s3; d = d3; off = i - n0 - n1 - n2; br = 3; }
  else return;
  float4 v = s[off];
  ushort4 o; o.x = f2b(v.x); o.y = f2b(v.y); o.z = f2b(v.z); o.w = f2b(v.w);
  *(ushort4*)(d + (size_t)off * 4) = o;
  if (br == 3) {   // also scatter into k^T[h][d][n]
    int flat = off * 4;
    int h = flat >> 16, rem = flat & 65535, n = rem >> 6, d4 = rem & 63;
    u16* kb = ktT + (h << 16) + (d4 << 10) + n;
    kb[0] = o.x; kb[1024] = o.y; kb[2048] = o.z; kb[3072] = o.w;
  }
}

// ---------------------------------------------------------------- K1: qv = x @ w_qv^T  (bf16 MFMA, m97 pattern)
// q-half blocks (n0<768) write q [B,H,N,D]; v-half blocks write V^T [B,H,D,N]
// directly (r-consecutive acc -> consecutive n: vectorized ushort4 stores).
__global__ __launch_bounds__(256) void qv_gemm(
    const u16* __restrict__ A, const u16* __restrict__ W,
    u16* __restrict__ qo, u16* __restrict__ vto)
{
  __shared__ u16 As[128*32];
  __shared__ u16 Bs[128*32];
  const int tid = threadIdx.x, lane = tid & 63, wid = tid >> 6;
  const int m0 = blockIdx.y * 128, n0 = blockIdx.x * 128;
  const int wm = (wid >> 1) * 64, wn = (wid & 1) * 64;
  const int lr = lane & 15, lq = lane >> 4;
  f32x4 acc[4][4] = {};
  for (int k0 = 0; k0 < 768; k0 += 32) {
#pragma unroll
    for (int it = 0; it < 2; ++it) {
      int c = it * 256 + tid;
      int row = c >> 2, c8 = c & 3;
      gl2lds16(A + (size_t)(m0 + row) * 768 + k0 + c8 * 8, (char*)As + (it*256 + wid*64) * 16);
      gl2lds16(W + (size_t)(n0 + row) * 768 + k0 + c8 * 8, (char*)Bs + (it*256 + wid*64) * 16);
    }
    __syncthreads();
    bf16x8 af[4], bfr[4];
#pragma unroll
    for (int i = 0; i < 4; ++i) {
      af[i]  = *(const bf16x8*)&As[(wm + i*16 + lr) * 32 + lq * 8];
      bfr[i] = *(const bf16x8*)&Bs[(wn + i*16 + lr) * 32 + lq * 8];
    }
#pragma unroll
    for (int mi = 0; mi < 4; ++mi)
#pragma unroll
      for (int nj = 0; nj < 4; ++nj)
        acc[mi][nj] = __builtin_amdgcn_mfma_f32_16x16x32_bf16(af[mi], bfr[nj], acc[mi][nj], 0, 0, 0);
    __syncthreads();
  }
  if (n0 < 768) {        // q-half (block-uniform branch)
#pragma unroll
    for (int mi = 0; mi < 4; ++mi)
#pragma unroll
      for (int nj = 0; nj < 4; ++nj)
#pragma unroll
        for (int r = 0; r < 4; ++r) {
          int row = m0 + wm + mi*16 + lq*4 + r;   // flat b*N+n
          int col = n0 + wn + nj*16 + lr;
          int b = row >> 10, n = row & 1023;
          int h = col >> 6, d = col & 63;
          qo[(((size_t)(b*12 + h)) << 16) + (n << 6) + d] = f2b(acc[mi][nj][r]);
        }
  } else {               // v-half -> V^T[b,h][d][n], vectorized over r (=n)
#pragma unroll
    for (int mi = 0; mi < 4; ++mi)
#pragma unroll
      for (int nj = 0; nj < 4; ++nj) {
        int rowb = m0 + wm + mi*16 + lq*4;        // 4-aligned, no 1024-crossing
        int b = rowb >> 10, n = rowb & 1023;
        int e = n0 + wn + nj*16 + lr - 768;
        int h = e >> 6, d = e & 63;
        ushort4 o;
        o.x = f2b(acc[mi][nj][0]); o.y = f2b(acc[mi][nj][1]);
        o.z = f2b(acc[mi][nj][2]); o.w = f2b(acc[mi][nj][3]);
        *(ushort4*)(vto + (((size_t)(b*12 + h)) << 16) + (d << 10) + n) = o;
      }
  }
}

// ---------------------------------------------------------------- K2: fused stats — one dispatch
// grid (53, 12h): x<16 -> qs+qsum partial (64 n-rows); x==16 -> ksum;
// x in [17,21) -> K-gram partial gx=x-17; x in [21,53) -> Q-gram partial gx=x-21.
__global__ __launch_bounds__(256) void stats_fused(
    const u16* __restrict__ q, const u16* __restrict__ k,
    float* __restrict__ qs, float* __restrict__ qsum, float* __restrict__ ksum,
    float* __restrict__ Kgp, float* __restrict__ Qgp)
{
  __shared__ float t[64*68];
  const int h = blockIdx.y, bx = blockIdx.x, tid = threadIdx.x;
  if (bx < 16) {
    const int n0b = bx * 64, d = tid & 63, rg = tid >> 6;
    float part = 0.f;
    for (int i = 0; i < 16; ++i) {
      int n = n0b + rg + 4*i;
      float s = 0.f;
#pragma unroll
      for (int b = 0; b < 8; ++b)
        s += b2f(q[(((size_t)(b*12 + h)) << 16) + (n << 6) + d]);
      qs[(((size_t)h) << 16) + (n << 6) + d] = s;
      part += s;
    }
    t[tid] = part; __syncthreads();
    if (rg == 0) atomicAdd(&qsum[h*64 + d], t[d] + t[64+d] + t[128+d] + t[192+d]);
  } else if (bx == 16) {
    const int d = tid & 63, rg = tid >> 6;
    float s = 0.f;
    for (int n = rg; n < 1024; n += 4)
      s += b2f(k[(((size_t)h) << 16) + (n << 6) + d]);
    t[tid] = s; __syncthreads();
    if (rg == 0) ksum[h*64 + d] = t[d] + t[64+d] + t[128+d] + t[192+d];
  } else {
    const int isQ = (bx >= 21);
    const int gx = isQ ? (bx - 21) : (bx - 17);
    const int r0 = gx * 256;
    const int rr = (tid >> 4) * 4, cc = (tid & 15) * 4;
    const u16* src = isQ ? q : k;
    float a[4][4] = {{0.f}};
    for (int t0 = 0; t0 < 256; t0 += 64) {
#pragma unroll
      for (int i = 0; i < 4; ++i) {
        int e = i*256 + tid; int r = e >> 4, d4 = (e & 15) * 4;
        int gr = r0 + t0 + r;
        size_t addr;
        if (isQ) { int b = gr >> 10, n = gr & 1023;
          addr = (((size_t)(b*12 + h)) << 16) + (n << 6) + d4; }
        else addr = (((size_t)h) << 16) + ((size_t)gr << 6) + d4;
        ushort4 u = *(const ushort4*)(src + addr);
        float4 f; f.x = b2f(u.x); f.y = b2f(u.y); f.z = b2f(u.z); f.w = b2f(u.w);
        *(float4*)&t[r*68 + d4] = f;
      }
      __syncthreads();
#pragma unroll 4
      for (int m = 0; m < 64; ++m) {
        float4 rv = *(const float4*)&t[m*68 + rr];
        float4 cv = *(const float4*)&t[m*68 + cc];
        a[0][0] += rv.x*cv.x; a[0][1] += rv.x*cv.y; a[0][2] += rv.x*cv.z; a[0][3] += rv.x*cv.w;
        a[1][0] += rv.y*cv.x; a[1][1] += rv.y*cv.y; a[1][2] += rv.y*cv.z; a[1][3] += rv.y*cv.w;
        a[2][0] += rv.z*cv.x; a[2][1] += rv.z*cv.y; a[2][2] += rv.z*cv.z; a[2][3] += rv.z*cv.w;
        a[3][0] += rv.w*cv.x; a[3][1] += rv.w*cv.y; a[3][2] += rv.w*cv.z; a[3][3] += rv.w*cv.w;
      }
      __syncthreads();
    }
    float* g = (isQ ? Qgp : Kgp) + (((size_t)gx) * 12 + h) * 4096;
#pragma unroll
    for (int i = 0; i < 4; ++i)
      *(float4*)&g[(rr + i)*64 + cc] = make_float4(a[i][0], a[i][1], a[i][2], a[i][3]);
  }
}

// ---------------------------------------------------------------- K2b: bias stats — register-only MFMA
__global__ __launch_bounds__(256) void bias_stats(
    const float* __restrict__ bias, const u16* __restrict__ ktT,
    const float* __restrict__ qs, float* __restrict__ acc)
{
  __shared__ float red[12];
  const int tid = threadIdx.x, lane = tid & 63, wid = tid >> 6;
  const int lr = lane & 15, lq = lane >> 4;
  const int h = blockIdx.y;
  const int nb = blockIdx.x & 15, mb = blockIdx.x >> 4;
  const int n0 = nb * 64 + wid * 16;          // wave's 16 n-rows
  const size_t brow = (((size_t)h) << 20) + ((size_t)(n0 + lr) << 10);
  const size_t kbase = ((size_t)h) << 16;
  f32x4 kb[4] = {};
  float sb = 0.f, sb2 = 0.f;
#pragma unroll
  for (int ms = 0; ms < 4; ++ms) {
    const int m0 = mb * 256 + ms * 64;
#pragma unroll
    for (int ks = 0; ks < 2; ++ks) {
      const int mc = m0 + ks * 32 + lq * 8;
      float4 b0 = *(const float4*)(bias + brow + mc);
      float4 b1 = *(const float4*)(bias + brow + mc + 4);
      sb  += b0.x + b0.y + b0.z + b0.w + b1.x + b1.y + b1.z + b1.w;
      sb2 += b0.x*b0.x + b0.y*b0.y + b0.z*b0.z + b0.w*b0.w
           + b1.x*b1.x + b1.y*b1.y + b1.z*b1.z + b1.w*b1.w;
      union { bf16x8 v; u16 u[8]; } af;
      af.u[0] = f2b(b0.x); af.u[1] = f2b(b0.y); af.u[2] = f2b(b0.z); af.u[3] = f2b(b0.w);
      af.u[4] = f2b(b1.x); af.u[5] = f2b(b1.y); af.u[6] = f2b(b1.z); af.u[7] = f2b(b1.w);
#pragma unroll
      for (int dj = 0; dj < 4; ++dj) {
        bf16x8 bfr = *(const bf16x8*)(ktT + kbase + (size_t)(dj*16 + lr) * 1024 + mc);
        kb[dj] = __builtin_amdgcn_mfma_f32_16x16x32_bf16(af.v, bfr, kb[dj], 0, 0, 0);
      }
    }
  }
  float cross = 0.f;
#pragma unroll
  for (int dj = 0; dj < 4; ++dj)
#pragma unroll
    for (int r = 0; r < 4; ++r)
      cross += kb[dj][r] *
               qs[kbase + ((size_t)(nb*64 + wid*16 + lq*4 + r) << 6) + dj*16 + lr];
#pragma unroll
  for (int s = 32; s; s >>= 1) {
    sb += __shfl_xor(sb, s); sb2 += __shfl_xor(sb2, s); cross += __shfl_xor(cross, s);
  }
  if (lane == 0) { red[wid] = sb; red[4 + wid] = sb2; red[8 + wid] = cross; }
  __syncthreads();
  if (tid == 0) {
    atomicAdd(acc + h,      red[0] + red[1] + red[2] + red[3]);
    atomicAdd(acc + 12 + h, red[4] + red[5] + red[6] + red[7]);
    atomicAdd(acc + 24 + h, red[8] + red[9] + red[10] + red[11]);
  }
}

// ---------------------------------------------------------------- K5: reduce gram partials + assemble var -> temp[h]
__global__ __launch_bounds__(256) void finalize_kernel(
    const float* __restrict__ qsum, const float* __restrict__ ksum,
    const float* __restrict__ Qgp, const float* __restrict__ Kgp,
    const float* __restrict__ acc, const float* __restrict__ gamma,
    float* __restrict__ temp)
{
  __shared__ float qg[4096];
  __shared__ float kg[4096];
  __shared__ float red[8];
  int h = blockIdx.x, tid = threadIdx.x, wid = tid >> 6, lane = tid & 63;
#pragma unroll
  for (int i = 0; i < 16; ++i) {
    int e = i*256 + tid;
    float q = 0.f, k = 0.f;
    for (int g = 0; g < GQ_; ++g) q += Qgp[(((size_t)g)*12 + h)*4096 + e];
#pragma unroll
    for (int g = 0; g < GK_; ++g) k += Kgp[(((size_t)g)*12 + h)*4096 + e];
    qg[e] = q; kg[e] = k;
  }
  __syncthreads();
  float s2 = 0.f;
#pragma unroll
  for (int i = 0; i < 16; ++i) { int e = i*256 + tid; s2 += qg[e]*kg[e]; }
  float s1 = (tid < 64) ? qsum[h*64 + tid] * ksum[h*64 + tid] : 0.f;
#pragma unroll
  for (int s = 32; s; s >>= 1) { s2 += __shfl_xor(s2, s); s1 += __shfl_xor(s1, s); }
  if (lane == 0) { red[wid] = s2; red[4 + wid] = s1; }
  __syncthreads();
  if (tid == 0) {
    double S2 = (double)red[0] + red[1] + red[2] + red[3];
    double S1 = (double)red[4];          // only wave 0 had s1 contributions
    double M = 8388608.0;                // B*N*N
    double Sb = acc[h], Sb2 = acc[12 + h], Cross = acc[24 + h];
    double Eraw  = (S1 + 8.0 * Sb) / M;
    double Eraw2 = (S2 + 2.0 * Cross + 8.0 * Sb2) / M;
    double var = (double)SCALE_ * (double)SCALE_ * (Eraw2 - Eraw * Eraw);
    double rstd = 1.0 / sqrt(var + 1e-5);
    temp[h] = (float)((double)gamma[h] * (double)SCALE_ * rstd);
  }
}

// ---------------------------------------------------------------- K6: fused flash attention v4 (unchanged this round)
__global__ __launch_bounds__(256) void attn_kernel(
    const u16* __restrict__ q, const u16* __restrict__ k, const u16* __restrict__ vT,
    const float* __restrict__ bias, const float* __restrict__ temp, u16* __restrict__ out)
{
  __shared__ u16 kt[4096];       // [2 ks][64 m][32 k]
  __shared__ u16 vt[5120];       // [2 ks][80 d][32 m]  (rows 64..79: ones-row pad)
  __shared__ u16 pt[128*72];     // [128 n][72] bf16 P round-trip
  const int tid = threadIdx.x, lane = tid & 63, wid = tid >> 6;
  const int lr = lane & 15, lq = lane >> 4;
  const int X = blockIdx.x;
  const int g = X >> 6, r_ = X & 63, b = r_ >> 3, q8 = r_ & 7;
  const int p = g*8 + q8;
  const int h = p % 12, n0 = (p / 12) * 128;
  const size_t qbase = ((((size_t)b) * 12 + h) << 16) + ((size_t)n0 << 6);
  const size_t kbase = ((size_t)h) << 16;
  const size_t vbase = ((((size_t)b) * 12 + h) << 16);
  const size_t bbase = (((size_t)h) << 20) + ((size_t)n0 << 10);
  const float tmp2 = temp[h] * 1.44269504f;   // fold log2(e)
  const int W = wid * 32;                     // wave's rows: W..W+31 (2 mi tiles)

  bf16x8 aq[2][2];
#pragma unroll
  for (int mi = 0; mi < 2; ++mi)
#pragma unroll
    for (int ks = 0; ks < 2; ++ks)
      aq[mi][ks] = *(const bf16x8*)(q + qbase + (size_t)(W + mi*16 + lr)*64 + ks*32 + lq*8);

  for (int i = tid; i < 1024; i += 256) {
    int ks = i >> 9, rr = (i >> 5) & 15, cc = i & 31;
    vt[ks*2560 + (64 + rr)*32 + cc] = (rr == 0) ? (u16)0x3F80 : (u16)0;
  }

  const float* br[2][4];
#pragma unroll
  for (int mi = 0; mi < 2; ++mi)
#pragma unroll
    for (int r = 0; r < 4; ++r)
      br[mi][r] = bias + bbase + (size_t)(W + mi*16 + lq*4 + r) * 1024 + lr;

  f32x4 oacc[5][2] = {};   // O^T: [dj d-tiles (4 + ones)][ni n-tiles]

  for (int m0 = 0; m0 < 1024; m0 += 64) {
#pragma unroll
    for (int it = 0; it < 2; ++it) {
      int c = it*256 + tid; int ks = c >> 8, r = (c >> 2) & 63, c8 = c & 3;
      gl2lds16(k  + kbase + (size_t)(m0 + r) * 64 + ks*32 + c8*8, (char*)kt + (it*256 + wid*64) * 16);
      gl2lds16(vT + vbase + (size_t)r * 1024 + m0 + ks*32 + c8*8, (char*)vt + it*5120 + wid*1024);
    }
    f32x4 s[2][4];
#pragma unroll
    for (int mi = 0; mi < 2; ++mi)
#pragma unroll
      for (int nj = 0; nj < 4; ++nj)
#pragma unroll
        for (int r = 0; r < 4; ++r)
          s[mi][nj][r] = br[mi][r][m0 + nj*16];
    __syncthreads();
#pragma unroll
    for (int ks = 0; ks < 2; ++ks) {
#pragma unroll
      for (int nj = 0; nj < 4; ++nj) {
        bf16x8 bk = *(const bf16x8*)&kt[ks*2048 + (nj*16 + lr)*32 + lq*8];
#pragma unroll
        for (int mi = 0; mi < 2; ++mi)
          s[mi][nj] = __builtin_amdgcn_mfma_f32_16x16x32_bf16(aq[mi][ks], bk, s[mi][nj], 0, 0, 0);
      }
    }
#pragma unroll
    for (int mi = 0; mi < 2; ++mi)
#pragma unroll
      for (int r = 0; r < 4; ++r) {
        int row = W + mi*16 + lq*4 + r;
#pragma unroll
        for (int nj = 0; nj < 4; ++nj)
          pt[row*72 + nj*16 + lr] = phu(exp2fast(s[mi][nj][r] * tmp2));
      }
#pragma unroll
    for (int ks = 0; ks < 2; ++ks) {
      bf16x8 bp[2];
#pragma unroll
      for (int ni = 0; ni < 2; ++ni)
        bp[ni] = *(const bf16x8*)&pt[(W + ni*16 + lr)*72 + ks*32 + lq*8];
#pragma unroll
      for (int dj = 0; dj < 5; ++dj) {
        bf16x8 av = *(const bf16x8*)&vt[ks*2560 + (dj*16 + lr)*32 + lq*8];
#pragma unroll
        for (int ni = 0; ni < 2; ++ni)
          oacc[dj][ni] = __builtin_amdgcn_mfma_f32_16x16x32_bf16(av, bp[ni], oacc[dj][ni], 0, 0, 0);
      }
    }
    __syncthreads();
  }
#pragma unroll
  for (int ni = 0; ni < 2; ++ni) {
    float l = __shfl(oacc[4][ni][0], lr);    // from lane (lq=0, lr)
    float linv = __builtin_amdgcn_rcpf(l);
    int n = n0 + W + ni*16 + lr;
    u16* orow = out + (size_t)(b*1024 + n) * 768 + h*64 + lq*4;
#pragma unroll
    for (int dj = 0; dj < 4; ++dj) {
      ushort4 o;
      o.x = f2b(oacc[dj][ni][0] * linv); o.y = f2b(oacc[dj][ni][1] * linv);
      o.z = f2b(oacc[dj][ni][2] * linv); o.w = f2b(oacc[dj][ni][3] * linv);
      *(ushort4*)(orow + dj*16) = o;
    }
  }
}

// ---------------------------------------------------------------- K7: out = attn @ w_proj^T + b_proj (fp32 out)
__global__ __launch_bounds__(256) void proj_gemm(
    const u16* __restrict__ A, const u16* __restrict__ W,
    const float* __restrict__ bp, float* __restrict__ out)
{
  __shared__ u16 As[128*32];
  __shared__ u16 Bs[128*32];
  const int tid = threadIdx.x, lane = tid & 63, wid = tid >> 6;
  const int m0 = blockIdx.y * 128, n0 = blockIdx.x * 128;
  const int wm = (wid >> 1) * 64, wn = (wid & 1) * 64;
  const int lr = lane & 15, lq = lane >> 4;
  f32x4 acc[4][4] = {};
  for (int k0 = 0; k0 < 768; k0 += 32) {
#pragma unroll
    for (int it = 0; it < 2; ++it) {
      int c = it*256 + tid; int row = c >> 2, c8 = c & 3;
      gl2lds16(A + (size_t)(m0 + row) * 768 + k0 + c8*8, (char*)As + (it*256 + wid*64) * 16);
      gl2lds16(W + (size_t)(n0 + row) * 768 + k0 + c8*8, (char*)Bs + (it*256 + wid*64) * 16);
    }
    __syncthreads();
    bf16x8 af[4], bfr[4];
#pragma unroll
    for (int i = 0; i < 4; ++i) {
      af[i]  = *(const bf16x8*)&As[(wm + i*16 + lr)*32 + lq*8];
      bfr[i] = *(const bf16x8*)&Bs[(wn + i*16 + lr)*32 + lq*8];
    }
#pragma unroll
    for (int mi = 0; mi < 4; ++mi)
#pragma unroll
      for (int nj = 0; nj < 4; ++nj)
        acc[mi][nj] = __builtin_amdgcn_mfma_f32_16x16x32_bf16(af[mi], bfr[nj], acc[mi][nj], 0, 0, 0);
    __syncthreads();
  }
#pragma unroll
  for (int mi = 0; mi < 4; ++mi)
#pragma unroll
    for (int nj = 0; nj < 4; ++nj)
#pragma unroll
      for (int r = 0; r < 4; ++r) {
        int row = m0 + wm + mi*16 + lq*4 + r;
        int col = n0 + wn + nj*16 + lr;
        out[(size_t)row * 768 + col] = acc[mi][nj][r] + bp[col];
      }
}

// ----------------------------------------------------------------
extern "C" void kernel_launch(void* const* d_in, const int* in_sizes, int n_in,
                              void* d_out, int out_size, void* d_ws, size_t ws_size,
                              hipStream_t stream)
{
  const float* x     = (const float*)d_in[0];
  const float* wqv   = (const float*)d_in[1];
  const float* ek    = (const float*)d_in[2];
  const float* ebias = (const float*)d_in[3];
  const float* gamma = (const float*)d_in[4];
  // d_in[5] = bn_beta: cancels inside softmax (per-row constant) — unused.
  const float* wp    = (const float*)d_in[6];
  const float* bp    = (const float*)d_in[7];
  float* out = (float*)d_out;

  char* ws = (char*)d_ws;
  size_t off = 0;
  auto alloc = [&](size_t bytes) { char* p = ws + off; off += (bytes + 255) & ~(size_t)255; return p; };
  u16* x16   = (u16*)alloc((size_t)8192*768*2);   // also reused: gram partials, attn output
  u16* wqv16 = (u16*)alloc((size_t)1536*768*2);
  u16* wp16  = (u16*)alloc((size_t)768*768*2);
  u16* k16   = (u16*)alloc((size_t)12*1024*64*2);
  u16* ktT16 = (u16*)alloc((size_t)12*64*1024*2);
  u16* q16   = (u16*)alloc((size_t)8*12*1024*64*2);
  u16* vt16  = (u16*)alloc((size_t)8*12*1024*64*2);
  float* qs  = (float*)alloc((size_t)12*1024*64*4);
  float* acc = (float*)alloc(3*12*4);          // zero region start
  float* qsum = (float*)alloc(12*64*4);
  float* ksum = (float*)alloc(12*64*4);
  int zfloats = (int)(((size_t)(((char*)ksum + 12*64*4) - (char*)acc)) / 4);
  float* temp = (float*)alloc(12*4);
  // Gram partials overlaid on x16 (dead after qv_gemm; partials dead after finalize)
  float* Qgp = (float*)x16;                    // 32*12*4096 f32 = 6.29 MB
  float* Kgp = Qgp + (size_t)GQ_*12*4096;      //  4*12*4096 f32 = 0.79 MB
  u16* attn16 = x16;                           // attn output reuses x16 after finalize

  { // K0: casts (x, w_qv, w_proj, ext_k) + ktT scatter + atomic-region zeroing
    int c0 = 8192*768/4, c1 = 1536*768/4, c2 = 768*768/4, c3 = 12*1024*64/4;
    int total = c0 + c1 + c2 + c3;
    cast_all<<<(total + 255)/256, 256, 0, stream>>>(
        (const float4*)x, x16, c0, (const float4*)wqv, wqv16, c1,
        (const float4*)wp, wp16, c2, (const float4*)ek, k16, c3,
        ktT16, acc, zfloats);
  }
  qv_gemm<<<dim3(12, 64), 256, 0, stream>>>(x16, wqv16, q16, vt16);
  stats_fused<<<dim3(53, 12), 256, 0, stream>>>(q16, k16, qs, qsum, ksum, Kgp, Qgp);
  bias_stats<<<dim3(64, 12), 256, 0, stream>>>(ebias, ktT16, qs, acc);
  finalize_kernel<<<12, 256, 0, stream>>>(qsum, ksum, Qgp, Kgp, acc, gamma, temp);
  attn_kernel<<<dim3(768), 256, 0, stream>>>(q16, k16, vt16, ebias, temp, attn16);
  proj_gemm<<<dim3(6, 64), 256, 0, stream>>>(attn16, wp16, bp, out);
}

// Round 8
// 295.370 us; speedup vs baseline: 1.1315x; 1.1315x over previous
//
#include <hip/hip_runtime.h>
#include <cstdint>

// Problem constants
#define B_    8
#define N_    1024
#define DIM_  768
#define H_    12
#define D_    64
#define SCALE_ 0.125f
#define GQ_   32   // partial-gram blocks per head for Q (8192 rows / 256)
#define GK_   4    // partial-gram blocks per head for K (1024 rows / 256)

typedef unsigned short u16;
typedef short bf16x8 __attribute__((ext_vector_type(8)));
typedef float f32x4  __attribute__((ext_vector_type(4)));

__device__ __forceinline__ u16 f2b(float f) {
  union { float f; unsigned u; } v; v.f = f;
  unsigned r = v.u + 0x7FFFu + ((v.u >> 16) & 1u);
  return (u16)(r >> 16);
}
// half-up round to bf16 (2 VALU ops; for positive non-NaN values)
__device__ __forceinline__ u16 phu(float f) {
  union { float f; unsigned u; } v; v.f = f;
  return (u16)((v.u + 0x8000u) >> 16);
}
__device__ __forceinline__ float b2f(u16 h) {
  union { unsigned u; float f; } v; v.u = ((unsigned)h) << 16; return v.f;
}
#if __has_builtin(__builtin_amdgcn_exp2f)
__device__ __forceinline__ float exp2fast(float x) { return __builtin_amdgcn_exp2f(x); }
#else
__device__ __forceinline__ float exp2fast(float x) { return __expf(x * 0.69314718f); }
#endif
// async global->LDS, 16B per lane; LDS base must be wave-uniform (HW adds lane*16)
__device__ __forceinline__ void gl2lds16(const void* g, void* l) {
  __builtin_amdgcn_global_load_lds(
      (const __attribute__((address_space(1))) void*)g,
      (__attribute__((address_space(3))) void*)l, 16, 0, 0);
}

// ---------------------------------------------------------------- K0: fp32 -> bf16 casts
// + branch-3 (ext_k) also writes k^T [H][64][1024]
// + block 0 zeroes the atomic-accumulator region (replaces hipMemsetAsync)
__global__ __launch_bounds__(256) void cast_all(
    const float4* __restrict__ s0, u16* __restrict__ d0, int n0,
    const float4* __restrict__ s1, u16* __restrict__ d1, int n1,
    const float4* __restrict__ s2, u16* __restrict__ d2, int n2,
    const float4* __restrict__ s3, u16* __restrict__ d3, int n3,
    u16* __restrict__ ktT, float* __restrict__ zptr, int zfloats)
{
  const int tid = threadIdx.x;
  if (blockIdx.x == 0)
    for (int j = tid; j < zfloats; j += 256) zptr[j] = 0.f;
  int i = blockIdx.x * 256 + tid;
  const float4* s; u16* d; int off; int br;
  if (i < n0)               { s = s0; d = d0; off = i; br = 0; }
  else if (i < n0+n1)       { s = s1; d = d1; off = i - n0; br = 1; }
  else if (i < n0+n1+n2)    { s = s2; d = d2; off = i - n0 - n1; br = 2; }
  else if (i < n0+n1+n2+n3) { s = s3; d = d3; off = i - n0 - n1 - n2; br = 3; }
  else return;
  float4 v = s[off];
  ushort4 o; o.x = f2b(v.x); o.y = f2b(v.y); o.z = f2b(v.z); o.w = f2b(v.w);
  *(ushort4*)(d + (size_t)off * 4) = o;
  if (br == 3) {   // also scatter into k^T[h][d][n]
    int flat = off * 4;
    int h = flat >> 16, rem = flat & 65535, n = rem >> 6, d4 = rem & 63;
    u16* kb = ktT + (h << 16) + (d4 << 10) + n;
    kb[0] = o.x; kb[1024] = o.y; kb[2048] = o.z; kb[3072] = o.w;
  }
}

// ---------------------------------------------------------------- K1: qv = x @ w_qv^T  (bf16 MFMA, m97 pattern)
// q-half blocks (n0<768) write q [B,H,N,D]; v-half blocks write V^T [B,H,D,N]
// directly (r-consecutive acc -> consecutive n: vectorized ushort4 stores).
__global__ __launch_bounds__(256) void qv_gemm(
    const u16* __restrict__ A, const u16* __restrict__ W,
    u16* __restrict__ qo, u16* __restrict__ vto)
{
  __shared__ u16 As[128*32];
  __shared__ u16 Bs[128*32];
  const int tid = threadIdx.x, lane = tid & 63, wid = tid >> 6;
  const int m0 = blockIdx.y * 128, n0 = blockIdx.x * 128;
  const int wm = (wid >> 1) * 64, wn = (wid & 1) * 64;
  const int lr = lane & 15, lq = lane >> 4;
  f32x4 acc[4][4] = {};
  for (int k0 = 0; k0 < 768; k0 += 32) {
#pragma unroll
    for (int it = 0; it < 2; ++it) {
      int c = it * 256 + tid;
      int row = c >> 2, c8 = c & 3;
      gl2lds16(A + (size_t)(m0 + row) * 768 + k0 + c8 * 8, (char*)As + (it*256 + wid*64) * 16);
      gl2lds16(W + (size_t)(n0 + row) * 768 + k0 + c8 * 8, (char*)Bs + (it*256 + wid*64) * 16);
    }
    __syncthreads();
    bf16x8 af[4], bfr[4];
#pragma unroll
    for (int i = 0; i < 4; ++i) {
      af[i]  = *(const bf16x8*)&As[(wm + i*16 + lr) * 32 + lq * 8];
      bfr[i] = *(const bf16x8*)&Bs[(wn + i*16 + lr) * 32 + lq * 8];
    }
#pragma unroll
    for (int mi = 0; mi < 4; ++mi)
#pragma unroll
      for (int nj = 0; nj < 4; ++nj)
        acc[mi][nj] = __builtin_amdgcn_mfma_f32_16x16x32_bf16(af[mi], bfr[nj], acc[mi][nj], 0, 0, 0);
    __syncthreads();
  }
  if (n0 < 768) {        // q-half (block-uniform branch)
#pragma unroll
    for (int mi = 0; mi < 4; ++mi)
#pragma unroll
      for (int nj = 0; nj < 4; ++nj)
#pragma unroll
        for (int r = 0; r < 4; ++r) {
          int row = m0 + wm + mi*16 + lq*4 + r;   // flat b*N+n
          int col = n0 + wn + nj*16 + lr;
          int b = row >> 10, n = row & 1023;
          int h = col >> 6, d = col & 63;
          qo[(((size_t)(b*12 + h)) << 16) + (n << 6) + d] = f2b(acc[mi][nj][r]);
        }
  } else {               // v-half -> V^T[b,h][d][n], vectorized over r (=n)
#pragma unroll
    for (int mi = 0; mi < 4; ++mi)
#pragma unroll
      for (int nj = 0; nj < 4; ++nj) {
        int rowb = m0 + wm + mi*16 + lq*4;        // 4-aligned, no 1024-crossing
        int b = rowb >> 10, n = rowb & 1023;
        int e = n0 + wn + nj*16 + lr - 768;
        int h = e >> 6, d = e & 63;
        ushort4 o;
        o.x = f2b(acc[mi][nj][0]); o.y = f2b(acc[mi][nj][1]);
        o.z = f2b(acc[mi][nj][2]); o.w = f2b(acc[mi][nj][3]);
        *(ushort4*)(vto + (((size_t)(b*12 + h)) << 16) + (d << 10) + n) = o;
      }
  }
}

// ---------------------------------------------------------------- K2: fused stats v2 — one dispatch, TLP restored
// grid (101, 12h):
//   x in [0,64)    -> qs + qsum partial (16 n-rows/block, ushort4 loads)
//   x in [64,68)   -> K-gram partial gx = x-64
//   x in [68,100)  -> Q-gram partial gx = x-68
//   x == 100       -> ksum (vectorized)
__global__ __launch_bounds__(256) void stats_fused(
    const u16* __restrict__ q, const u16* __restrict__ k,
    float* __restrict__ qs, float* __restrict__ qsum, float* __restrict__ ksum,
    float* __restrict__ Kgp, float* __restrict__ Qgp)
{
  __shared__ float t[64*68];
  const int h = blockIdx.y, bx = blockIdx.x, tid = threadIdx.x;
  if (bx < 64) {
    const int nl = tid >> 4, d4 = (tid & 15) * 4;
    const int n = bx * 16 + nl;
    float4 s = {0.f, 0.f, 0.f, 0.f};
#pragma unroll
    for (int b = 0; b < 8; ++b) {
      ushort4 u = *(const ushort4*)(q + (((size_t)(b*12 + h)) << 16) + (n << 6) + d4);
      s.x += b2f(u.x); s.y += b2f(u.y); s.z += b2f(u.z); s.w += b2f(u.w);
    }
    *(float4*)(qs + (((size_t)h) << 16) + (n << 6) + d4) = s;
    *(float4*)&t[nl*68 + d4] = s;
    __syncthreads();
    if (tid < 64) {
      float a = 0.f;
#pragma unroll
      for (int i = 0; i < 16; ++i) a += t[i*68 + tid];
      atomicAdd(&qsum[h*64 + tid], a);
    }
  } else if (bx == 100) {
    const int nl = tid >> 4, d4 = (tid & 15) * 4;
    float4 s = {0.f, 0.f, 0.f, 0.f};
    for (int n = nl; n < 1024; n += 16) {
      ushort4 u = *(const ushort4*)(k + (((size_t)h) << 16) + (n << 6) + d4);
      s.x += b2f(u.x); s.y += b2f(u.y); s.z += b2f(u.z); s.w += b2f(u.w);
    }
    *(float4*)&t[nl*68 + d4] = s;
    __syncthreads();
    if (tid < 64) {
      float a = 0.f;
#pragma unroll
      for (int i = 0; i < 16; ++i) a += t[i*68 + tid];
      ksum[h*64 + tid] = a;
    }
  } else {
    const int isQ = (bx >= 68);
    const int gx = isQ ? (bx - 68) : (bx - 64);
    const int r0 = gx * 256;
    const int rr = (tid >> 4) * 4, cc = (tid & 15) * 4;
    const u16* src = isQ ? q : k;
    float a[4][4] = {{0.f}};
    for (int t0 = 0; t0 < 256; t0 += 64) {
#pragma unroll
      for (int i = 0; i < 4; ++i) {
        int e = i*256 + tid; int r = e >> 4, d4 = (e & 15) * 4;
        int gr = r0 + t0 + r;
        size_t addr;
        if (isQ) { int b = gr >> 10, n = gr & 1023;
          addr = (((size_t)(b*12 + h)) << 16) + (n << 6) + d4; }
        else addr = (((size_t)h) << 16) + ((size_t)gr << 6) + d4;
        ushort4 u = *(const ushort4*)(src + addr);
        float4 f; f.x = b2f(u.x); f.y = b2f(u.y); f.z = b2f(u.z); f.w = b2f(u.w);
        *(float4*)&t[r*68 + d4] = f;
      }
      __syncthreads();
#pragma unroll 4
      for (int m = 0; m < 64; ++m) {
        float4 rv = *(const float4*)&t[m*68 + rr];
        float4 cv = *(const float4*)&t[m*68 + cc];
        a[0][0] += rv.x*cv.x; a[0][1] += rv.x*cv.y; a[0][2] += rv.x*cv.z; a[0][3] += rv.x*cv.w;
        a[1][0] += rv.y*cv.x; a[1][1] += rv.y*cv.y; a[1][2] += rv.y*cv.z; a[1][3] += rv.y*cv.w;
        a[2][0] += rv.z*cv.x; a[2][1] += rv.z*cv.y; a[2][2] += rv.z*cv.z; a[2][3] += rv.z*cv.w;
        a[3][0] += rv.w*cv.x; a[3][1] += rv.w*cv.y; a[3][2] += rv.w*cv.z; a[3][3] += rv.w*cv.w;
      }
      __syncthreads();
    }
    float* g = (isQ ? Qgp : Kgp) + (((size_t)gx) * 12 + h) * 4096;
#pragma unroll
    for (int i = 0; i < 4; ++i)
      *(float4*)&g[(rr + i)*64 + cc] = make_float4(a[i][0], a[i][1], a[i][2], a[i][3]);
  }
}

// ---------------------------------------------------------------- K2b: bias stats — register-only MFMA
__global__ __launch_bounds__(256) void bias_stats(
    const float* __restrict__ bias, const u16* __restrict__ ktT,
    const float* __restrict__ qs, float* __restrict__ acc)
{
  __shared__ float red[12];
  const int tid = threadIdx.x, lane = tid & 63, wid = tid >> 6;
  const int lr = lane & 15, lq = lane >> 4;
  const int h = blockIdx.y;
  const int nb = blockIdx.x & 15, mb = blockIdx.x >> 4;
  const int n0 = nb * 64 + wid * 16;          // wave's 16 n-rows
  const size_t brow = (((size_t)h) << 20) + ((size_t)(n0 + lr) << 10);
  const size_t kbase = ((size_t)h) << 16;
  f32x4 kb[4] = {};
  float sb = 0.f, sb2 = 0.f;
#pragma unroll
  for (int ms = 0; ms < 4; ++ms) {
    const int m0 = mb * 256 + ms * 64;
#pragma unroll
    for (int ks = 0; ks < 2; ++ks) {
      const int mc = m0 + ks * 32 + lq * 8;
      float4 b0 = *(const float4*)(bias + brow + mc);
      float4 b1 = *(const float4*)(bias + brow + mc + 4);
      sb  += b0.x + b0.y + b0.z + b0.w + b1.x + b1.y + b1.z + b1.w;
      sb2 += b0.x*b0.x + b0.y*b0.y + b0.z*b0.z + b0.w*b0.w
           + b1.x*b1.x + b1.y*b1.y + b1.z*b1.z + b1.w*b1.w;
      union { bf16x8 v; u16 u[8]; } af;
      af.u[0] = f2b(b0.x); af.u[1] = f2b(b0.y); af.u[2] = f2b(b0.z); af.u[3] = f2b(b0.w);
      af.u[4] = f2b(b1.x); af.u[5] = f2b(b1.y); af.u[6] = f2b(b1.z); af.u[7] = f2b(b1.w);
#pragma unroll
      for (int dj = 0; dj < 4; ++dj) {
        bf16x8 bfr = *(const bf16x8*)(ktT + kbase + (size_t)(dj*16 + lr) * 1024 + mc);
        kb[dj] = __builtin_amdgcn_mfma_f32_16x16x32_bf16(af.v, bfr, kb[dj], 0, 0, 0);
      }
    }
  }
  float cross = 0.f;
#pragma unroll
  for (int dj = 0; dj < 4; ++dj)
#pragma unroll
    for (int r = 0; r < 4; ++r)
      cross += kb[dj][r] *
               qs[kbase + ((size_t)(nb*64 + wid*16 + lq*4 + r) << 6) + dj*16 + lr];
#pragma unroll
  for (int s = 32; s; s >>= 1) {
    sb += __shfl_xor(sb, s); sb2 += __shfl_xor(sb2, s); cross += __shfl_xor(cross, s);
  }
  if (lane == 0) { red[wid] = sb; red[4 + wid] = sb2; red[8 + wid] = cross; }
  __syncthreads();
  if (tid == 0) {
    atomicAdd(acc + h,      red[0] + red[1] + red[2] + red[3]);
    atomicAdd(acc + 12 + h, red[4] + red[5] + red[6] + red[7]);
    atomicAdd(acc + 24 + h, red[8] + red[9] + red[10] + red[11]);
  }
}

// ---------------------------------------------------------------- K5: reduce gram partials + assemble var -> temp[h]
__global__ __launch_bounds__(256) void finalize_kernel(
    const float* __restrict__ qsum, const float* __restrict__ ksum,
    const float* __restrict__ Qgp, const float* __restrict__ Kgp,
    const float* __restrict__ acc, const float* __restrict__ gamma,
    float* __restrict__ temp)
{
  __shared__ float qg[4096];
  __shared__ float kg[4096];
  __shared__ float red[8];
  int h = blockIdx.x, tid = threadIdx.x, wid = tid >> 6, lane = tid & 63;
#pragma unroll
  for (int i = 0; i < 16; ++i) {
    int e = i*256 + tid;
    float q = 0.f, k = 0.f;
    for (int g = 0; g < GQ_; ++g) q += Qgp[(((size_t)g)*12 + h)*4096 + e];
#pragma unroll
    for (int g = 0; g < GK_; ++g) k += Kgp[(((size_t)g)*12 + h)*4096 + e];
    qg[e] = q; kg[e] = k;
  }
  __syncthreads();
  float s2 = 0.f;
#pragma unroll
  for (int i = 0; i < 16; ++i) { int e = i*256 + tid; s2 += qg[e]*kg[e]; }
  float s1 = (tid < 64) ? qsum[h*64 + tid] * ksum[h*64 + tid] : 0.f;
#pragma unroll
  for (int s = 32; s; s >>= 1) { s2 += __shfl_xor(s2, s); s1 += __shfl_xor(s1, s); }
  if (lane == 0) { red[wid] = s2; red[4 + wid] = s1; }
  __syncthreads();
  if (tid == 0) {
    double S2 = (double)red[0] + red[1] + red[2] + red[3];
    double S1 = (double)red[4];          // only wave 0 had s1 contributions
    double M = 8388608.0;                // B*N*N
    double Sb = acc[h], Sb2 = acc[12 + h], Cross = acc[24 + h];
    double Eraw  = (S1 + 8.0 * Sb) / M;
    double Eraw2 = (S2 + 2.0 * Cross + 8.0 * Sb2) / M;
    double var = (double)SCALE_ * (double)SCALE_ * (Eraw2 - Eraw * Eraw);
    double rstd = 1.0 / sqrt(var + 1e-5);
    temp[h] = (float)((double)gamma[h] * (double)SCALE_ * rstd);
  }
}

// ---------------------------------------------------------------- K6: fused flash attention v4 (unchanged)
__global__ __launch_bounds__(256) void attn_kernel(
    const u16* __restrict__ q, const u16* __restrict__ k, const u16* __restrict__ vT,
    const float* __restrict__ bias, const float* __restrict__ temp, u16* __restrict__ out)
{
  __shared__ u16 kt[4096];       // [2 ks][64 m][32 k]
  __shared__ u16 vt[5120];       // [2 ks][80 d][32 m]  (rows 64..79: ones-row pad)
  __shared__ u16 pt[128*72];     // [128 n][72] bf16 P round-trip
  const int tid = threadIdx.x, lane = tid & 63, wid = tid >> 6;
  const int lr = lane & 15, lq = lane >> 4;
  const int X = blockIdx.x;
  const int g = X >> 6, r_ = X & 63, b = r_ >> 3, q8 = r_ & 7;
  const int p = g*8 + q8;
  const int h = p % 12, n0 = (p / 12) * 128;
  const size_t qbase = ((((size_t)b) * 12 + h) << 16) + ((size_t)n0 << 6);
  const size_t kbase = ((size_t)h) << 16;
  const size_t vbase = ((((size_t)b) * 12 + h) << 16);
  const size_t bbase = (((size_t)h) << 20) + ((size_t)n0 << 10);
  const float tmp2 = temp[h] * 1.44269504f;   // fold log2(e)
  const int W = wid * 32;                     // wave's rows: W..W+31 (2 mi tiles)

  bf16x8 aq[2][2];
#pragma unroll
  for (int mi = 0; mi < 2; ++mi)
#pragma unroll
    for (int ks = 0; ks < 2; ++ks)
      aq[mi][ks] = *(const bf16x8*)(q + qbase + (size_t)(W + mi*16 + lr)*64 + ks*32 + lq*8);

  for (int i = tid; i < 1024; i += 256) {
    int ks = i >> 9, rr = (i >> 5) & 15, cc = i & 31;
    vt[ks*2560 + (64 + rr)*32 + cc] = (rr == 0) ? (u16)0x3F80 : (u16)0;
  }

  const float* br[2][4];
#pragma unroll
  for (int mi = 0; mi < 2; ++mi)
#pragma unroll
    for (int r = 0; r < 4; ++r)
      br[mi][r] = bias + bbase + (size_t)(W + mi*16 + lq*4 + r) * 1024 + lr;

  f32x4 oacc[5][2] = {};   // O^T: [dj d-tiles (4 + ones)][ni n-tiles]

  for (int m0 = 0; m0 < 1024; m0 += 64) {
#pragma unroll
    for (int it = 0; it < 2; ++it) {
      int c = it*256 + tid; int ks = c >> 8, r = (c >> 2) & 63, c8 = c & 3;
      gl2lds16(k  + kbase + (size_t)(m0 + r) * 64 + ks*32 + c8*8, (char*)kt + (it*256 + wid*64) * 16);
      gl2lds16(vT + vbase + (size_t)r * 1024 + m0 + ks*32 + c8*8, (char*)vt + it*5120 + wid*1024);
    }
    f32x4 s[2][4];
#pragma unroll
    for (int mi = 0; mi < 2; ++mi)
#pragma unroll
      for (int nj = 0; nj < 4; ++nj)
#pragma unroll
        for (int r = 0; r < 4; ++r)
          s[mi][nj][r] = br[mi][r][m0 + nj*16];
    __syncthreads();
#pragma unroll
    for (int ks = 0; ks < 2; ++ks) {
#pragma unroll
      for (int nj = 0; nj < 4; ++nj) {
        bf16x8 bk = *(const bf16x8*)&kt[ks*2048 + (nj*16 + lr)*32 + lq*8];
#pragma unroll
        for (int mi = 0; mi < 2; ++mi)
          s[mi][nj] = __builtin_amdgcn_mfma_f32_16x16x32_bf16(aq[mi][ks], bk, s[mi][nj], 0, 0, 0);
      }
    }
#pragma unroll
    for (int mi = 0; mi < 2; ++mi)
#pragma unroll
      for (int r = 0; r < 4; ++r) {
        int row = W + mi*16 + lq*4 + r;
#pragma unroll
        for (int nj = 0; nj < 4; ++nj)
          pt[row*72 + nj*16 + lr] = phu(exp2fast(s[mi][nj][r] * tmp2));
      }
#pragma unroll
    for (int ks = 0; ks < 2; ++ks) {
      bf16x8 bp[2];
#pragma unroll
      for (int ni = 0; ni < 2; ++ni)
        bp[ni] = *(const bf16x8*)&pt[(W + ni*16 + lr)*72 + ks*32 + lq*8];
#pragma unroll
      for (int dj = 0; dj < 5; ++dj) {
        bf16x8 av = *(const bf16x8*)&vt[ks*2560 + (dj*16 + lr)*32 + lq*8];
#pragma unroll
        for (int ni = 0; ni < 2; ++ni)
          oacc[dj][ni] = __builtin_amdgcn_mfma_f32_16x16x32_bf16(av, bp[ni], oacc[dj][ni], 0, 0, 0);
      }
    }
    __syncthreads();
  }
#pragma unroll
  for (int ni = 0; ni < 2; ++ni) {
    float l = __shfl(oacc[4][ni][0], lr);    // from lane (lq=0, lr)
    float linv = __builtin_amdgcn_rcpf(l);
    int n = n0 + W + ni*16 + lr;
    u16* orow = out + (size_t)(b*1024 + n) * 768 + h*64 + lq*4;
#pragma unroll
    for (int dj = 0; dj < 4; ++dj) {
      ushort4 o;
      o.x = f2b(oacc[dj][ni][0] * linv); o.y = f2b(oacc[dj][ni][1] * linv);
      o.z = f2b(oacc[dj][ni][2] * linv); o.w = f2b(oacc[dj][ni][3] * linv);
      *(ushort4*)(orow + dj*16) = o;
    }
  }
}

// ---------------------------------------------------------------- K7: out = attn @ w_proj^T + b_proj (fp32 out)
__global__ __launch_bounds__(256) void proj_gemm(
    const u16* __restrict__ A, const u16* __restrict__ W,
    const float* __restrict__ bp, float* __restrict__ out)
{
  __shared__ u16 As[128*32];
  __shared__ u16 Bs[128*32];
  const int tid = threadIdx.x, lane = tid & 63, wid = tid >> 6;
  const int m0 = blockIdx.y * 128, n0 = blockIdx.x * 128;
  const int wm = (wid >> 1) * 64, wn = (wid & 1) * 64;
  const int lr = lane & 15, lq = lane >> 4;
  f32x4 acc[4][4] = {};
  for (int k0 = 0; k0 < 768; k0 += 32) {
#pragma unroll
    for (int it = 0; it < 2; ++it) {
      int c = it*256 + tid; int row = c >> 2, c8 = c & 3;
      gl2lds16(A + (size_t)(m0 + row) * 768 + k0 + c8*8, (char*)As + (it*256 + wid*64) * 16);
      gl2lds16(W + (size_t)(n0 + row) * 768 + k0 + c8*8, (char*)Bs + (it*256 + wid*64) * 16);
    }
    __syncthreads();
    bf16x8 af[4], bfr[4];
#pragma unroll
    for (int i = 0; i < 4; ++i) {
      af[i]  = *(const bf16x8*)&As[(wm + i*16 + lr)*32 + lq*8];
      bfr[i] = *(const bf16x8*)&Bs[(wn + i*16 + lr)*32 + lq*8];
    }
#pragma unroll
    for (int mi = 0; mi < 4; ++mi)
#pragma unroll
      for (int nj = 0; nj < 4; ++nj)
        acc[mi][nj] = __builtin_amdgcn_mfma_f32_16x16x32_bf16(af[mi], bfr[nj], acc[mi][nj], 0, 0, 0);
    __syncthreads();
  }
#pragma unroll
  for (int mi = 0; mi < 4; ++mi)
#pragma unroll
    for (int nj = 0; nj < 4; ++nj)
#pragma unroll
      for (int r = 0; r < 4; ++r) {
        int row = m0 + wm + mi*16 + lq*4 + r;
        int col = n0 + wn + nj*16 + lr;
        out[(size_t)row * 768 + col] = acc[mi][nj][r] + bp[col];
      }
}

// ----------------------------------------------------------------
extern "C" void kernel_launch(void* const* d_in, const int* in_sizes, int n_in,
                              void* d_out, int out_size, void* d_ws, size_t ws_size,
                              hipStream_t stream)
{
  const float* x     = (const float*)d_in[0];
  const float* wqv   = (const float*)d_in[1];
  const float* ek    = (const float*)d_in[2];
  const float* ebias = (const float*)d_in[3];
  const float* gamma = (const float*)d_in[4];
  // d_in[5] = bn_beta: cancels inside softmax (per-row constant) — unused.
  const float* wp    = (const float*)d_in[6];
  const float* bp    = (const float*)d_in[7];
  float* out = (float*)d_out;

  char* ws = (char*)d_ws;
  size_t off = 0;
  auto alloc = [&](size_t bytes) { char* p = ws + off; off += (bytes + 255) & ~(size_t)255; return p; };
  u16* x16   = (u16*)alloc((size_t)8192*768*2);   // also reused: gram partials, attn output
  u16* wqv16 = (u16*)alloc((size_t)1536*768*2);
  u16* wp16  = (u16*)alloc((size_t)768*768*2);
  u16* k16   = (u16*)alloc((size_t)12*1024*64*2);
  u16* ktT16 = (u16*)alloc((size_t)12*64*1024*2);
  u16* q16   = (u16*)alloc((size_t)8*12*1024*64*2);
  u16* vt16  = (u16*)alloc((size_t)8*12*1024*64*2);
  float* qs  = (float*)alloc((size_t)12*1024*64*4);
  float* acc = (float*)alloc(3*12*4);          // zero region start
  float* qsum = (float*)alloc(12*64*4);
  float* ksum = (float*)alloc(12*64*4);
  int zfloats = (int)(((size_t)(((char*)ksum + 12*64*4) - (char*)acc)) / 4);
  float* temp = (float*)alloc(12*4);
  // Gram partials overlaid on x16 (dead after qv_gemm; partials dead after finalize)
  float* Qgp = (float*)x16;                    // 32*12*4096 f32 = 6.29 MB
  float* Kgp = Qgp + (size_t)GQ_*12*4096;      //  4*12*4096 f32 = 0.79 MB
  u16* attn16 = x16;                           // attn output reuses x16 after finalize

  { // K0: casts (x, w_qv, w_proj, ext_k) + ktT scatter + atomic-region zeroing
    int c0 = 8192*768/4, c1 = 1536*768/4, c2 = 768*768/4, c3 = 12*1024*64/4;
    int total = c0 + c1 + c2 + c3;
    cast_all<<<(total + 255)/256, 256, 0, stream>>>(
        (const float4*)x, x16, c0, (const float4*)wqv, wqv16, c1,
        (const float4*)wp, wp16, c2, (const float4*)ek, k16, c3,
        ktT16, acc, zfloats);
  }
  qv_gemm<<<dim3(12, 64), 256, 0, stream>>>(x16, wqv16, q16, vt16);
  stats_fused<<<dim3(101, 12), 256, 0, stream>>>(q16, k16, qs, qsum, ksum, Kgp, Qgp);
  bias_stats<<<dim3(64, 12), 256, 0, stream>>>(ebias, ktT16, qs, acc);
  finalize_kernel<<<12, 256, 0, stream>>>(qsum, ksum, Qgp, Kgp, acc, gamma, temp);
  attn_kernel<<<dim3(768), 256, 0, stream>>>(q16, k16, vt16, ebias, temp, attn16);
  proj_gemm<<<dim3(6, 64), 256, 0, stream>>>(attn16, wp16, bp, out);
}